// Round 1
// baseline (248.665 us; speedup 1.0000x reference)
//
#include <hip/hip_runtime.h>
#include <hip/hip_bf16.h>

// out[n,d] = b[d] + pk[n,d] + max_m ok[n,m,d]
//   pk = p @ Wp^T  (2048x1024,  K=1024)
//   ok = o @ Wo^T  (65536x1024, K=1024)  -- 137.4 GFLOP, dominant
// Structure: bf16 convert pass -> small pk GEMM (pk+b into ws) ->
// m97-style 128x128 MFMA GEMM with fused max-over-32-rows epilogue.

#define NN 2048
#define MM 32
#define CC 1024

typedef __attribute__((ext_vector_type(8))) __bf16 bf16x8;
typedef __attribute__((ext_vector_type(4))) float f32x4;
typedef __attribute__((ext_vector_type(8))) unsigned short u16x8;

__device__ inline unsigned short f2bf(float f) {
  union { __hip_bfloat16 h; unsigned short u; } v;
  v.h = __float2bfloat16(f);
  return v.u;
}

__device__ inline void gload_lds16(const void* g, void* l) {
  __builtin_amdgcn_global_load_lds(
      (const __attribute__((address_space(1))) void*)g,
      (__attribute__((address_space(3))) void*)l, 16, 0, 0);
}

// ---- convert other_features (67,108,864 f32) -> bf16 ----
__global__ void conv_o(const float* __restrict__ src,
                       unsigned short* __restrict__ dst, int total8) {
  int i = blockIdx.x * blockDim.x + threadIdx.x;
  int stride = gridDim.x * blockDim.x;
  for (; i < total8; i += stride) {
    const float4* s = reinterpret_cast<const float4*>(src) + (size_t)i * 2;
    float4 a = s[0], b = s[1];
    u16x8 r;
    r[0] = f2bf(a.x); r[1] = f2bf(a.y); r[2] = f2bf(a.z); r[3] = f2bf(a.w);
    r[4] = f2bf(b.x); r[5] = f2bf(b.y); r[6] = f2bf(b.z); r[7] = f2bf(b.w);
    *reinterpret_cast<u16x8*>(dst + (size_t)i * 8) = r;
  }
}

// ---- convert person_features + split W into Wp/Wo (bf16) ----
__global__ void conv_pw(const float* __restrict__ p, const float* __restrict__ W,
                        unsigned short* __restrict__ pd,
                        unsigned short* __restrict__ wp,
                        unsigned short* __restrict__ wo) {
  const int PG = (NN * CC) / 8;        // 262144
  const int WG = (CC * 2 * CC) / 8;    // 262144
  int i = blockIdx.x * blockDim.x + threadIdx.x;
  int stride = gridDim.x * blockDim.x;
  for (; i < PG + WG; i += stride) {
    if (i < PG) {
      const float4* s = reinterpret_cast<const float4*>(p) + (size_t)i * 2;
      float4 a = s[0], b = s[1];
      u16x8 r;
      r[0] = f2bf(a.x); r[1] = f2bf(a.y); r[2] = f2bf(a.z); r[3] = f2bf(a.w);
      r[4] = f2bf(b.x); r[5] = f2bf(b.y); r[6] = f2bf(b.z); r[7] = f2bf(b.w);
      *reinterpret_cast<u16x8*>(pd + (size_t)i * 8) = r;
    } else {
      int f = i - PG;
      int e = f * 8;
      int d = e >> 11;          // W row (2048 cols per row)
      int cc = e & 2047;
      const float4* s = reinterpret_cast<const float4*>(W) + (size_t)f * 2;
      float4 a = s[0], b = s[1];
      u16x8 r;
      r[0] = f2bf(a.x); r[1] = f2bf(a.y); r[2] = f2bf(a.z); r[3] = f2bf(a.w);
      r[4] = f2bf(b.x); r[5] = f2bf(b.y); r[6] = f2bf(b.z); r[7] = f2bf(b.w);
      unsigned short* o = (cc < CC) ? (wp + (size_t)d * CC + cc)
                                    : (wo + (size_t)d * CC + (cc - CC));
      *reinterpret_cast<u16x8*>(o) = r;
    }
  }
}

// ---- 128x128 bf16 GEMM, B^T layout (both A and B row-major with K contiguous).
// FUSE==0: out[row,col] = acc + bvec[col]            (pk+b into ws)
// FUSE==1: out[n,col]   = max over 32 rows + pkb[n,col]  (final output)
// grid.x = nrow_tiles*8 (8 col tiles of 128 over C=1024), K fixed = 1024.
template <int FUSE>
__global__ void gemm_bt(const unsigned short* __restrict__ A,
                        const unsigned short* __restrict__ B,
                        const float* __restrict__ pkb,
                        const float* __restrict__ bvec,
                        float* __restrict__ out) {
  __shared__ unsigned short As[128 * 64];
  __shared__ unsigned short Bs[128 * 64];

  int nb = gridDim.x;
  int chunk = nb >> 3;                     // blocks per XCD
  int obid = blockIdx.x;
  int vb = (obid & 7) * chunk + (obid >> 3);  // XCD-contiguous, col-fastest
  int bcol = vb & 7;
  int brow = vb >> 3;

  int tid = threadIdx.x;
  int l = tid & 63;
  int wid = tid >> 6;
  int wr = wid >> 1, wc = wid & 1;
  int lr = l & 15;
  int lk = (l >> 4) << 3;

  const unsigned short* gA = A + (size_t)brow * 128 * CC;
  const unsigned short* gB = B + (size_t)bcol * 128 * CC;

  f32x4 acc[4][4] = {};

  for (int kt = 0; kt < 16; ++kt) {
    int k0 = kt * 64;
#pragma unroll
    for (int j = 0; j < 4; ++j) {
      int f = (j * 256 + tid) * 8;  // elem index into 128x64 tile
      int r = f >> 6;
      int c = f & 63;
      gload_lds16(gA + (size_t)r * CC + k0 + c, &As[f]);
      gload_lds16(gB + (size_t)r * CC + k0 + c, &Bs[f]);
    }
    __syncthreads();
#pragma unroll
    for (int kk = 0; kk < 2; ++kk) {
      bf16x8 af[4], bfr[4];
#pragma unroll
      for (int mi = 0; mi < 4; ++mi)
        af[mi] = *reinterpret_cast<const bf16x8*>(
            &As[(wr * 64 + mi * 16 + lr) * 64 + kk * 32 + lk]);
#pragma unroll
      for (int ni = 0; ni < 4; ++ni)
        bfr[ni] = *reinterpret_cast<const bf16x8*>(
            &Bs[(wc * 64 + ni * 16 + lr) * 64 + kk * 32 + lk]);
#pragma unroll
      for (int mi = 0; mi < 4; ++mi)
#pragma unroll
        for (int ni = 0; ni < 4; ++ni)
          acc[mi][ni] = __builtin_amdgcn_mfma_f32_16x16x32_bf16(
              af[mi], bfr[ni], acc[mi][ni], 0, 0, 0);
    }
    __syncthreads();
  }

  if (FUSE == 0) {
    // plain write: pk + b
#pragma unroll
    for (int mi = 0; mi < 4; ++mi) {
      int row = brow * 128 + wr * 64 + mi * 16 + (l >> 4) * 4;
#pragma unroll
      for (int ni = 0; ni < 4; ++ni) {
        int col = bcol * 128 + wc * 64 + ni * 16 + lr;
        float bb = bvec[col];
#pragma unroll
        for (int r = 0; r < 4; ++r)
          out[(size_t)(row + r) * CC + col] = acc[mi][ni][r] + bb;
      }
    }
  } else {
    // fused max over m (32 consecutive A rows per n) + pkb add
#pragma unroll
    for (int g = 0; g < 2; ++g) {
      int n = brow * 4 + wr * 2 + g;
#pragma unroll
      for (int ni = 0; ni < 4; ++ni) {
        float v = -3.402823466e38f;
#pragma unroll
        for (int mi = 2 * g; mi < 2 * g + 2; ++mi)
#pragma unroll
          for (int r = 0; r < 4; ++r)
            v = fmaxf(v, acc[mi][ni][r]);
        v = fmaxf(v, __shfl_xor(v, 16));
        v = fmaxf(v, __shfl_xor(v, 32));
        if (l < 16) {
          int col = bcol * 128 + wc * 64 + ni * 16 + l;
          out[(size_t)n * CC + col] = v + pkb[(size_t)n * CC + col];
        }
      }
    }
  }
}

extern "C" void kernel_launch(void* const* d_in, const int* in_sizes, int n_in,
                              void* d_out, int out_size, void* d_ws, size_t ws_size,
                              hipStream_t stream) {
  const float* p = (const float*)d_in[0];   // (N, C, 1, 1)
  const float* o = (const float*)d_in[1];   // (N, M, C, 1, 1)
  const float* W = (const float*)d_in[5];   // (C, 2C)
  const float* b = (const float*)d_in[6];   // (C,)
  float* out = (float*)d_out;               // (N, C, 1, 1)

  char* ws = (char*)d_ws;
  unsigned short* o_bf  = (unsigned short*)ws;                      // 134,217,728 B
  unsigned short* p_bf  = (unsigned short*)(ws + 134217728);        // 4 MB
  unsigned short* wp_bf = (unsigned short*)(ws + 138412032);        // 2 MB
  unsigned short* wo_bf = (unsigned short*)(ws + 140509184);        // 2 MB
  float*          pkb   = (float*)(ws + 142606336);                 // 8 MB

  conv_o<<<2048, 256, 0, stream>>>(o, o_bf, (NN * MM * CC) / 8);
  conv_pw<<<512, 256, 0, stream>>>(p, W, p_bf, wp_bf, wo_bf);
  // pk+b: 2048x1024 -> 16 row tiles x 8 col tiles = 128 blocks
  gemm_bt<0><<<128, 256, 0, stream>>>(p_bf, wp_bf, nullptr, b, pkb);
  // main: 65536x1024 -> 512 row tiles x 8 col tiles = 4096 blocks
  gemm_bt<1><<<4096, 256, 0, stream>>>(o_bf, wo_bf, pkb, nullptr, out);
}

// Round 2
// 222.744 us; speedup vs baseline: 1.1164x; 1.1164x over previous
//
#include <hip/hip_runtime.h>
#include <hip/hip_bf16.h>

// out[n,d] = b[d] + pk[n,d] + max_m ok[n,m,d]
//   pk = p @ Wp^T  (2048x1024,  K=1024)   -- small, 128-tile kernel
//   ok = o @ Wo^T  (65536x1024, K=1024)   -- 137.4 GFLOP, 256^2 8-phase kernel
// 8-phase: BK=64, 8 waves (2Mx4N), 128KiB LDS dbuf, counted vmcnt(6),
// XOR-swizzled LDS (inverse-swizzled global src + swizzled ds_read),
// setprio around MFMA clusters, fused max-over-32-rows epilogue.

#define NN 2048
#define MM 32
#define CC 1024

typedef __attribute__((ext_vector_type(8))) __bf16 bf16x8;
typedef __attribute__((ext_vector_type(4))) float f32x4;
typedef __attribute__((ext_vector_type(8))) unsigned short u16x8;

__device__ inline unsigned short f2bf(float f) {
  union { __hip_bfloat16 h; unsigned short u; } v;
  v.h = __float2bfloat16(f);
  return v.u;
}

__device__ inline void gload_lds16(const void* g, void* l) {
  __builtin_amdgcn_global_load_lds(
      (const __attribute__((address_space(1))) void*)g,
      (__attribute__((address_space(3))) void*)l, 16, 0, 0);
}

// ---- convert other_features (67,108,864 f32) -> bf16 ----
__global__ void conv_o(const float* __restrict__ src,
                       unsigned short* __restrict__ dst, int total8) {
  int i = blockIdx.x * blockDim.x + threadIdx.x;
  int stride = gridDim.x * blockDim.x;
  for (; i < total8; i += stride) {
    const float4* s = reinterpret_cast<const float4*>(src) + (size_t)i * 2;
    float4 a = s[0], b = s[1];
    u16x8 r;
    r[0] = f2bf(a.x); r[1] = f2bf(a.y); r[2] = f2bf(a.z); r[3] = f2bf(a.w);
    r[4] = f2bf(b.x); r[5] = f2bf(b.y); r[6] = f2bf(b.z); r[7] = f2bf(b.w);
    *reinterpret_cast<u16x8*>(dst + (size_t)i * 8) = r;
  }
}

// ---- convert person_features + split W into Wp/Wo (bf16) ----
__global__ void conv_pw(const float* __restrict__ p, const float* __restrict__ W,
                        unsigned short* __restrict__ pd,
                        unsigned short* __restrict__ wp,
                        unsigned short* __restrict__ wo) {
  const int PG = (NN * CC) / 8;
  const int WG = (CC * 2 * CC) / 8;
  int i = blockIdx.x * blockDim.x + threadIdx.x;
  int stride = gridDim.x * blockDim.x;
  for (; i < PG + WG; i += stride) {
    if (i < PG) {
      const float4* s = reinterpret_cast<const float4*>(p) + (size_t)i * 2;
      float4 a = s[0], b = s[1];
      u16x8 r;
      r[0] = f2bf(a.x); r[1] = f2bf(a.y); r[2] = f2bf(a.z); r[3] = f2bf(a.w);
      r[4] = f2bf(b.x); r[5] = f2bf(b.y); r[6] = f2bf(b.z); r[7] = f2bf(b.w);
      *reinterpret_cast<u16x8*>(pd + (size_t)i * 8) = r;
    } else {
      int f = i - PG;
      int e = f * 8;
      int d = e >> 11;
      int cc = e & 2047;
      const float4* s = reinterpret_cast<const float4*>(W) + (size_t)f * 2;
      float4 a = s[0], b = s[1];
      u16x8 r;
      r[0] = f2bf(a.x); r[1] = f2bf(a.y); r[2] = f2bf(a.z); r[3] = f2bf(a.w);
      r[4] = f2bf(b.x); r[5] = f2bf(b.y); r[6] = f2bf(b.z); r[7] = f2bf(b.w);
      unsigned short* o = (cc < CC) ? (wp + (size_t)d * CC + cc)
                                    : (wo + (size_t)d * CC + (cc - CC));
      *reinterpret_cast<u16x8*>(o) = r;
    }
  }
}

// ---- small 128x128 GEMM for pk+b (m97 structure, plenty for 4.3 GFLOP) ----
__global__ void gemm_pk(const unsigned short* __restrict__ A,
                        const unsigned short* __restrict__ B,
                        const float* __restrict__ bvec,
                        float* __restrict__ out) {
  __shared__ unsigned short As[128 * 64];
  __shared__ unsigned short Bs[128 * 64];

  int nb = gridDim.x;
  int chunk = nb >> 3;
  int obid = blockIdx.x;
  int vb = (obid & 7) * chunk + (obid >> 3);
  int bcol = vb & 7;
  int brow = vb >> 3;

  int tid = threadIdx.x;
  int l = tid & 63;
  int wid = tid >> 6;
  int wr = wid >> 1, wc = wid & 1;
  int lr = l & 15;
  int lk = (l >> 4) << 3;

  const unsigned short* gA = A + (size_t)brow * 128 * CC;
  const unsigned short* gB = B + (size_t)bcol * 128 * CC;

  f32x4 acc[4][4] = {};

  for (int kt = 0; kt < 16; ++kt) {
    int k0 = kt * 64;
#pragma unroll
    for (int j = 0; j < 4; ++j) {
      int f = (j * 256 + tid) * 8;
      int r = f >> 6;
      int c = f & 63;
      gload_lds16(gA + (size_t)r * CC + k0 + c, &As[f]);
      gload_lds16(gB + (size_t)r * CC + k0 + c, &Bs[f]);
    }
    __syncthreads();
#pragma unroll
    for (int kk = 0; kk < 2; ++kk) {
      bf16x8 af[4], bfr[4];
#pragma unroll
      for (int mi = 0; mi < 4; ++mi)
        af[mi] = *reinterpret_cast<const bf16x8*>(
            &As[(wr * 64 + mi * 16 + lr) * 64 + kk * 32 + lk]);
#pragma unroll
      for (int ni = 0; ni < 4; ++ni)
        bfr[ni] = *reinterpret_cast<const bf16x8*>(
            &Bs[(wc * 64 + ni * 16 + lr) * 64 + kk * 32 + lk]);
#pragma unroll
      for (int mi = 0; mi < 4; ++mi)
#pragma unroll
        for (int ni = 0; ni < 4; ++ni)
          acc[mi][ni] = __builtin_amdgcn_mfma_f32_16x16x32_bf16(
              af[mi], bfr[ni], acc[mi][ni], 0, 0, 0);
    }
    __syncthreads();
  }

#pragma unroll
  for (int mi = 0; mi < 4; ++mi) {
    int row = brow * 128 + wr * 64 + mi * 16 + (l >> 4) * 4;
#pragma unroll
    for (int ni = 0; ni < 4; ++ni) {
      int col = bcol * 128 + wc * 64 + ni * 16 + lr;
      float bb = bvec[col];
#pragma unroll
      for (int r = 0; r < 4; ++r)
        out[(size_t)(row + r) * CC + col] = acc[mi][ni][r] + bb;
    }
  }
}

// ==================== 256x256 8-phase main GEMM ====================
// grid: 256 row-tiles x 4 col-tiles = 1024 blocks, 512 threads.
// LDS per K-tile buf: A 256x64 bf16 (32KB) + B 256x64 (32KB); 2 bufs = 128KB.
// Swizzle: LDS cell (row, chunk16B) holds global (row, chunk ^ (row&7)).

#define BARRIER                                      \
  do {                                               \
    asm volatile("" ::: "memory");                   \
    __builtin_amdgcn_s_barrier();                    \
    asm volatile("" ::: "memory");                   \
  } while (0)

#define LGKM0 asm volatile("s_waitcnt lgkmcnt(0)" ::: "memory")

// stage one half-tile (128 rows x 64 cols) of A (isB=0) or B (isB=1),
// K-tile buffer bufidx, half h, k-offset k0. 2 x global_load_lds per thread.
#define STAGE(gsrc, bufidx, isB, h, k0)                                       \
  do {                                                                        \
    _Pragma("unroll") for (int ii = 0; ii < 2; ++ii)                          \
        gload_lds16(gsrc + (size_t)((h) * 128 + ii * 64 + rr) * CC + (k0) + sc, \
                    lds + (bufidx) * 65536 + (isB) * 32768 + (h) * 16384 +    \
                        ii * 8192 + tid * 16);                                \
  } while (0)

#define DSREAD_A(bufo, mq)                                                    \
  do {                                                                        \
    _Pragma("unroll") for (int i = 0; i < 4; ++i) {                           \
      af[i][0] = *(const bf16x8*)(lds + (bufo) + a_base0 + (mq) * 8192 + i * 2048); \
      af[i][1] = *(const bf16x8*)(lds + (bufo) + a_base1 + (mq) * 8192 + i * 2048); \
    }                                                                         \
  } while (0)

#define DSREAD_B(bufo, nq)                                                    \
  do {                                                                        \
    _Pragma("unroll") for (int j = 0; j < 2; ++j) {                           \
      bfr[(nq) * 2 + j][0] =                                                  \
          *(const bf16x8*)(lds + (bufo) + b_base0 + ((nq) * 2 + j) * 2048);   \
      bfr[(nq) * 2 + j][1] =                                                  \
          *(const bf16x8*)(lds + (bufo) + b_base1 + ((nq) * 2 + j) * 2048);   \
    }                                                                         \
  } while (0)

#define MFMA16(mq, nq)                                                        \
  do {                                                                        \
    __builtin_amdgcn_s_setprio(1);                                            \
    _Pragma("unroll") for (int i = 0; i < 4; ++i)                             \
        _Pragma("unroll") for (int j = 0; j < 2; ++j) {                       \
      acc[(mq) * 4 + i][(nq) * 2 + j] = __builtin_amdgcn_mfma_f32_16x16x32_bf16( \
          af[i][0], bfr[(nq) * 2 + j][0], acc[(mq) * 4 + i][(nq) * 2 + j], 0, 0, 0); \
      acc[(mq) * 4 + i][(nq) * 2 + j] = __builtin_amdgcn_mfma_f32_16x16x32_bf16( \
          af[i][1], bfr[(nq) * 2 + j][1], acc[(mq) * 4 + i][(nq) * 2 + j], 0, 0, 0); \
    }                                                                         \
    __builtin_amdgcn_s_setprio(0);                                            \
  } while (0)

// 4 phases of one K-tile t living in buffer offset bufo ((t&1)*65536).
// Staging ring (3 half-tiles ahead): ph1 -> (t+1).A1, ph3 -> (t+2).B0,
// ph4 -> (t+2).B1 + (t+2).A0. vmcnt(6) once per K-tile (phase 4).
#define TILE(t, bufo)                                                         \
  do {                                                                        \
    DSREAD_A(bufo, 0);                                                        \
    DSREAD_B(bufo, 0);                                                        \
    if ((t) + 1 < 16) STAGE(gA, ((t) + 1) & 1, 0, 1, ((t) + 1) * 64);         \
    BARRIER; LGKM0;                                                           \
    MFMA16(0, 0);                                                             \
    BARRIER;                                                                  \
    DSREAD_B(bufo, 1);                                                        \
    BARRIER; LGKM0;                                                           \
    MFMA16(0, 1);                                                             \
    BARRIER;                                                                  \
    DSREAD_A(bufo, 1);                                                        \
    if ((t) + 2 < 16) STAGE(gB, (t) & 1, 1, 0, ((t) + 2) * 64);               \
    BARRIER; LGKM0;                                                           \
    MFMA16(1, 0);                                                             \
    BARRIER;                                                                  \
    if ((t) + 2 < 16) {                                                       \
      STAGE(gB, (t) & 1, 1, 1, ((t) + 2) * 64);                               \
      STAGE(gA, (t) & 1, 0, 0, ((t) + 2) * 64);                               \
    }                                                                         \
    BARRIER; LGKM0;                                                           \
    MFMA16(1, 1);                                                             \
    if ((t) < 14) { asm volatile("s_waitcnt vmcnt(6)" ::: "memory"); }        \
    else          { asm volatile("s_waitcnt vmcnt(0)" ::: "memory"); }        \
    BARRIER;                                                                  \
  } while (0)

__global__ __launch_bounds__(512, 2) void gemm8ph(
    const unsigned short* __restrict__ A,
    const unsigned short* __restrict__ B,
    const float* __restrict__ pkb,
    float* __restrict__ out) {
  __shared__ char lds[131072];

  int obid = blockIdx.x;                    // 1024 blocks
  int vb = (obid & 7) * 128 + (obid >> 3);  // XCD-contiguous (1024 % 8 == 0)
  int bcol = vb & 3;                        // 4 col tiles
  int brow = vb >> 2;                       // 256 row tiles

  int tid = threadIdx.x;
  int l = tid & 63;
  int wid = tid >> 6;
  int wr = wid >> 2;   // 0..1
  int wc = wid & 3;    // 0..3
  int lr = l & 15;
  int g = l >> 4;      // 0..3

  const unsigned short* gA = A + (size_t)brow * 256 * CC;
  const unsigned short* gB = B + (size_t)bcol * 256 * CC;

  // staging addressing: thread writes LDS rows (tid>>3), chunk tid&7;
  // source chunk is XOR-swizzled so linear LDS write lands swizzled.
  int rr = tid >> 3;                         // 0..63 (row within 64-row chunk)
  int sc = ((tid & 7) ^ (rr & 7)) * 8;       // swizzled source col (elements)

  // ds_read byte offsets (within buffer): row R, chunk (kk*4+g)^(R&7); R&7==lr&7
  int axor = lr & 7;
  int a_base0 = (wr * 128 + lr) * 128 + ((g ^ axor) * 16);
  int a_base1 = (wr * 128 + lr) * 128 + (((4 + g) ^ axor) * 16);
  int b_base0 = 32768 + (wc * 64 + lr) * 128 + ((g ^ axor) * 16);
  int b_base1 = 32768 + (wc * 64 + lr) * 128 + (((4 + g) ^ axor) * 16);

  f32x4 acc[8][4] = {};
  bf16x8 af[4][2];
  bf16x8 bfr[4][2];

  // prologue: tile0 all 4 halves, tile1 B0,B1,A0 (A1 comes at tile0.ph1)
  STAGE(gB, 0, 1, 0, 0);
  STAGE(gB, 0, 1, 1, 0);
  STAGE(gA, 0, 0, 0, 0);
  STAGE(gA, 0, 0, 1, 0);
  STAGE(gB, 1, 1, 0, 64);
  STAGE(gB, 1, 1, 1, 64);
  STAGE(gA, 1, 0, 0, 64);
  asm volatile("s_waitcnt vmcnt(6)" ::: "memory");
  BARRIER;

#pragma unroll 1
  for (int tt = 0; tt < 16; tt += 2) {
    TILE(tt, 0);
    TILE(tt + 1, 65536);
  }

  // fused epilogue: max over 32 consecutive A-rows per n, + pkb
  int colb = bcol * 256 + wc * 64;
#pragma unroll
  for (int a = 0; a < 4; ++a) {
    int n = brow * 8 + wr * 4 + a;
#pragma unroll
    for (int ni = 0; ni < 4; ++ni) {
      float v = -3.402823466e38f;
#pragma unroll
      for (int mi = 2 * a; mi < 2 * a + 2; ++mi)
#pragma unroll
        for (int r = 0; r < 4; ++r) v = fmaxf(v, acc[mi][ni][r]);
      v = fmaxf(v, __shfl_xor(v, 16));
      v = fmaxf(v, __shfl_xor(v, 32));
      if (l < 16) {
        int col = colb + ni * 16 + l;
        out[(size_t)n * CC + col] = v + pkb[(size_t)n * CC + col];
      }
    }
  }
}

extern "C" void kernel_launch(void* const* d_in, const int* in_sizes, int n_in,
                              void* d_out, int out_size, void* d_ws, size_t ws_size,
                              hipStream_t stream) {
  const float* p = (const float*)d_in[0];   // (N, C, 1, 1)
  const float* o = (const float*)d_in[1];   // (N, M, C, 1, 1)
  const float* W = (const float*)d_in[5];   // (C, 2C)
  const float* b = (const float*)d_in[6];   // (C,)
  float* out = (float*)d_out;               // (N, C, 1, 1)

  char* ws = (char*)d_ws;
  unsigned short* o_bf  = (unsigned short*)ws;                      // 134,217,728 B
  unsigned short* p_bf  = (unsigned short*)(ws + 134217728);        // 4 MB
  unsigned short* wp_bf = (unsigned short*)(ws + 138412032);        // 2 MB
  unsigned short* wo_bf = (unsigned short*)(ws + 140509184);        // 2 MB
  float*          pkb   = (float*)(ws + 142606336);                 // 8 MB

  conv_o<<<2048, 256, 0, stream>>>(o, o_bf, (NN * MM * CC) / 8);
  conv_pw<<<512, 256, 0, stream>>>(p, W, p_bf, wp_bf, wo_bf);
  // pk+b: 2048x1024 -> 16 row tiles x 8 col tiles = 128 blocks
  gemm_pk<<<128, 256, 0, stream>>>(p_bf, wp_bf, b, pkb);
  // main: 65536x1024 -> 256 row tiles x 4 col tiles = 1024 blocks, 512 thr
  gemm8ph<<<1024, 512, 0, stream>>>(o_bf, wo_bf, pkb, out);
}